// Round 5
// baseline (2273.307 us; speedup 1.0000x reference)
//
#include <hip/hip_runtime.h>

// GAE scan: T=2048, N=4096, fp32. SINGLE-PASS decoupled-lookback scan
// (CUB/rocPRIM pattern), one kernel:
//   1. block takes a TICKET (atomic) -> processes chunk c = C-1-ticket for its
//      256-col4 stripe. Tickets guarantee ticket k only waits on tickets < k,
//      which belong to already-started blocks => deadlock-free under ANY
//      dispatch order (no co-residency assumption — round-3 lesson).
//   2. compute chunk affine (A,P), stash delta/cc in regs (64 VGPRs only —
//      round-3 lesson: small stash => no spill), publish aggregate + flag=1.
//   3. lookback: walk predecessors, composing aggregates until a published
//      prefix (flag=2) or the scan start; aggA/aggP/pre are 4 MiB each =>
//      L2-resident, typical depth 1-2.
//   4. publish own inclusive prefix (flag=2), then replay chunk from the
//      register stash (values re-read L1-hot) and write advantages+returns.
// Traffic: one input read (100 MB) + output write (67 MB) + L2-hot 12 MiB
// intermediates. Cross-XCD visibility: threadfence + agent-scope atomic flag
// (the exact pattern that gave correct results in rounds 2-3).

#define T_LEN    2048
#define N_ENV    4096
#define NV4      (N_ENV / 4)        // 1024 float4 columns
#define CP_C     256                // chunks (tickets per stripe)
#define CP_L     (T_LEN / CP_C)     // 8 timesteps per chunk
#define NSTRIPE  4
#define SCOLS    (NV4 / NSTRIPE)    // 256 col4 per stripe = blockDim
#define NBLK     (NSTRIPE * CP_C)   // 1024 blocks

static constexpr float GAMMA = 0.99f;
static constexpr float GL    = 0.99f * 0.95f;   // gamma * gae_lambda

__global__ __launch_bounds__(256) void gae_onepass(
    const float4* __restrict__ rewards,   // [T_LEN][NV4]
    const float4* __restrict__ values,
    const float4* __restrict__ dones,
    float4* __restrict__ aggA,            // [NSTRIPE*CP_C][SCOLS] 4 MiB
    float4* __restrict__ aggP,            // 4 MiB
    float4* __restrict__ pre,             // 4 MiB (inclusive prefix values)
    int*    __restrict__ flags,           // [NSTRIPE*CP_C] 0=none 1=agg 2=prefix
    int*    __restrict__ tickets,         // [NSTRIPE]
    float4* __restrict__ out)             // [2*T_LEN][NV4]: advantages, returns
{
    __shared__ int s_ticket;
    __shared__ int s_flag;

    const int stripe = blockIdx.x & (NSTRIPE - 1);
    if (threadIdx.x == 0)
        s_ticket = __hip_atomic_fetch_add(&tickets[stripe], 1,
                                          __ATOMIC_RELAXED,
                                          __HIP_MEMORY_SCOPE_AGENT);
    __syncthreads();
    const int k   = s_ticket;             // 0 = chunk CP_C-1 (latest time)
    const int c   = CP_C - 1 - k;
    const int col = stripe * SCOLS + threadIdx.x;
    const int t_hi = c * CP_L + (CP_L - 1);

    float4 v_next, d_next;
    if (c == CP_C - 1) {
        v_next = make_float4(0.f, 0.f, 0.f, 0.f);
        d_next = make_float4(1.f, 1.f, 1.f, 1.f);
    } else {
        v_next = values[(t_hi + 1) * NV4 + col];
        d_next = dones [(t_hi + 1) * NV4 + col];
    }

    // Chunk affine + register stash (fully unrolled => static indices).
    float4 dl[CP_L], cc[CP_L];
    float4 A = make_float4(1.f, 1.f, 1.f, 1.f);
    float4 P = make_float4(0.f, 0.f, 0.f, 0.f);

    #pragma unroll
    for (int i = 0; i < CP_L; ++i) {
        const int t = t_hi - i;
        const float4 r = rewards[t * NV4 + col];
        const float4 v = values [t * NV4 + col];
        const float4 d = dones  [t * NV4 + col];
        float4 dli, cci;
        #define STEP(X) { \
            const float nt    = 1.0f - d_next.X; \
            const float delta = fmaf(GAMMA * v_next.X, nt, r.X) - v.X; \
            const float co    = GL * nt; \
            dli.X = delta; cci.X = co; \
            P.X = fmaf(co, P.X, delta); \
            A.X = co * A.X; \
            v_next.X = v.X; d_next.X = d.X; }
        STEP(x) STEP(y) STEP(z) STEP(w)
        #undef STEP
        dl[i] = dli; cc[i] = cci;
    }

    // Publish aggregate (flag=1).
    const int fidx = stripe * CP_C + k;
    const int base = fidx * SCOLS + threadIdx.x;
    aggA[base] = A;
    aggP[base] = P;
    __threadfence();       // release A/P past per-XCD L2
    __syncthreads();       // all threads' stores fenced before the flag
    if (threadIdx.x == 0)
        __hip_atomic_store(&flags[fidx], 1, __ATOMIC_RELEASE,
                           __HIP_MEMORY_SCOPE_AGENT);

    // Lookback: x = exclusive prefix = adv entering this chunk from above.
    // Invariant: x = Ca * x_j + Cp, walking j = k-1 .. 0 (x_{-1} = 0).
    float4 Ca = make_float4(1.f, 1.f, 1.f, 1.f);
    float4 Cp = make_float4(0.f, 0.f, 0.f, 0.f);
    float4 x  = make_float4(0.f, 0.f, 0.f, 0.f);
    int  j   = k - 1;
    bool fin = (j < 0);                   // k==0: x stays 0
    while (!fin) {
        if (threadIdx.x == 0) {
            int f;
            do {
                f = __hip_atomic_load(&flags[stripe * CP_C + j],
                                      __ATOMIC_ACQUIRE,
                                      __HIP_MEMORY_SCOPE_AGENT);
                if (f == 0) __builtin_amdgcn_s_sleep(1);
            } while (f == 0);             // safe: ticket j already started
            s_flag = f;
        }
        __syncthreads();
        __threadfence();                  // acquire: no stale lines for data
        const int f  = s_flag;
        const int jb = (stripe * CP_C + j) * SCOLS + threadIdx.x;
        if (f == 2) {                     // predecessor's full prefix known
            const float4 xj = pre[jb];
            x.x = fmaf(Ca.x, xj.x, Cp.x);
            x.y = fmaf(Ca.y, xj.y, Cp.y);
            x.z = fmaf(Ca.z, xj.z, Cp.z);
            x.w = fmaf(Ca.w, xj.w, Cp.w);
            fin = true;
        } else {                          // only aggregate: fold and keep going
            const float4 Aj = aggA[jb];
            const float4 Pj = aggP[jb];
            Cp.x = fmaf(Ca.x, Pj.x, Cp.x);  Ca.x *= Aj.x;
            Cp.y = fmaf(Ca.y, Pj.y, Cp.y);  Ca.y *= Aj.y;
            Cp.z = fmaf(Ca.z, Pj.z, Cp.z);  Ca.z *= Aj.z;
            Cp.w = fmaf(Ca.w, Pj.w, Cp.w);  Ca.w *= Aj.w;
            if (--j < 0) { x = Cp; fin = true; }
        }
        __syncthreads();                  // s_flag consumed before next poll
    }

    // Publish inclusive prefix (flag=2) ASAP to unblock successors.
    float4 xk;
    xk.x = fmaf(A.x, x.x, P.x);
    xk.y = fmaf(A.y, x.y, P.y);
    xk.z = fmaf(A.z, x.z, P.z);
    xk.w = fmaf(A.w, x.w, P.w);
    pre[base] = xk;
    __threadfence();
    __syncthreads();
    if (threadIdx.x == 0)
        __hip_atomic_store(&flags[fidx], 2, __ATOMIC_RELEASE,
                           __HIP_MEMORY_SCOPE_AGENT);

    // Replay from the register stash; values re-read is L1-hot.
    float4 adv = x;
    #pragma unroll
    for (int i = 0; i < CP_L; ++i) {
        const int t = t_hi - i;
        const float4 v = values[t * NV4 + col];
        float4 ret;
        adv.x = fmaf(cc[i].x, adv.x, dl[i].x);  ret.x = adv.x + v.x;
        adv.y = fmaf(cc[i].y, adv.y, dl[i].y);  ret.y = adv.y + v.y;
        adv.z = fmaf(cc[i].z, adv.z, dl[i].z);  ret.z = adv.z + v.z;
        adv.w = fmaf(cc[i].w, adv.w, dl[i].w);  ret.w = adv.w + v.w;
        out[t * NV4 + col]           = adv;   // advantages
        out[(T_LEN + t) * NV4 + col] = ret;   // returns
    }
}

// ---- fallback: proven round-0 2-kernel path (used only if ws too small) ----
#define FB_CHUNKS 128
#define FB_L      16

__global__ __launch_bounds__(256) void gae_phase1_fb(
    const float4* __restrict__ rewards,
    const float4* __restrict__ values,
    const float4* __restrict__ dones,
    float4* __restrict__ Aout,
    float4* __restrict__ Pout)
{
    const int idx = blockIdx.x * blockDim.x + threadIdx.x;
    const int n4 = idx & (NV4 - 1);
    const int c  = idx >> 10;
    const int t_hi = c * FB_L + (FB_L - 1);

    float4 v_next, d_next;
    if (c == FB_CHUNKS - 1) {
        v_next = make_float4(0.f, 0.f, 0.f, 0.f);
        d_next = make_float4(1.f, 1.f, 1.f, 1.f);
    } else {
        v_next = values[(t_hi + 1) * NV4 + n4];
        d_next = dones [(t_hi + 1) * NV4 + n4];
    }
    float4 A = make_float4(1.f, 1.f, 1.f, 1.f);
    float4 P = make_float4(0.f, 0.f, 0.f, 0.f);
    #pragma unroll
    for (int i = 0; i < FB_L; ++i) {
        const int t = t_hi - i;
        const float4 r = rewards[t * NV4 + n4];
        const float4 v = values [t * NV4 + n4];
        const float4 d = dones  [t * NV4 + n4];
        #define STEP(X) { \
            const float nt    = 1.0f - d_next.X; \
            const float delta = fmaf(GAMMA * v_next.X, nt, r.X) - v.X; \
            const float co    = GL * nt; \
            P.X = fmaf(co, P.X, delta); \
            A.X = co * A.X; \
            v_next.X = v.X; d_next.X = d.X; }
        STEP(x) STEP(y) STEP(z) STEP(w)
        #undef STEP
    }
    Aout[idx] = A;
    Pout[idx] = P;
}

__global__ __launch_bounds__(256) void gae_phase23_fb(
    const float4* __restrict__ rewards,
    const float4* __restrict__ values,
    const float4* __restrict__ dones,
    const float4* __restrict__ Ain,
    const float4* __restrict__ Pin,
    float4* __restrict__ out)
{
    const int idx = blockIdx.x * blockDim.x + threadIdx.x;
    const int n4 = idx & (NV4 - 1);
    const int c  = idx >> 10;
    const int t_hi = c * FB_L + (FB_L - 1);

    float4 adv = make_float4(0.f, 0.f, 0.f, 0.f);
    #pragma unroll 4
    for (int c2 = FB_CHUNKS - 1; c2 > c; --c2) {
        const float4 a = Ain[c2 * NV4 + n4];
        const float4 p = Pin[c2 * NV4 + n4];
        adv.x = fmaf(a.x, adv.x, p.x);
        adv.y = fmaf(a.y, adv.y, p.y);
        adv.z = fmaf(a.z, adv.z, p.z);
        adv.w = fmaf(a.w, adv.w, p.w);
    }
    float4 v_next, d_next;
    if (c == FB_CHUNKS - 1) {
        v_next = make_float4(0.f, 0.f, 0.f, 0.f);
        d_next = make_float4(1.f, 1.f, 1.f, 1.f);
    } else {
        v_next = values[(t_hi + 1) * NV4 + n4];
        d_next = dones [(t_hi + 1) * NV4 + n4];
    }
    #pragma unroll
    for (int i = 0; i < FB_L; ++i) {
        const int t = t_hi - i;
        const float4 r = rewards[t * NV4 + n4];
        const float4 v = values [t * NV4 + n4];
        const float4 d = dones  [t * NV4 + n4];
        float4 ret;
        #define STEP(X) { \
            const float nt    = 1.0f - d_next.X; \
            const float delta = fmaf(GAMMA * v_next.X, nt, r.X) - v.X; \
            const float co    = GL * nt; \
            adv.X = fmaf(co, adv.X, delta); \
            ret.X = adv.X + v.X; \
            v_next.X = v.X; d_next.X = d.X; }
        STEP(x) STEP(y) STEP(z) STEP(w)
        #undef STEP
        out[t * NV4 + n4]           = adv;
        out[(T_LEN + t) * NV4 + n4] = ret;
    }
}

extern "C" void kernel_launch(void* const* d_in, const int* in_sizes, int n_in,
                              void* d_out, int out_size, void* d_ws, size_t ws_size,
                              hipStream_t stream) {
    const float4* rewards = (const float4*)d_in[0];
    const float4* values  = (const float4*)d_in[1];
    const float4* dones   = (const float4*)d_in[2];
    float4* out = (float4*)d_out;

    // Workspace layout: aggA | aggP | pre (4 MiB each) | flags (4 KiB) |
    // tickets (16 B). flags+tickets memset to 0 each launch (poison safe,
    // graph-capturable — proven in rounds 3-4). agg/pre fully written before
    // read via the flag protocol.
    const size_t entries = (size_t)NBLK * SCOLS;           // 262144 float4
    float4* aggA = (float4*)d_ws;
    float4* aggP = aggA + entries;
    float4* pre  = aggP + entries;
    int*    flags   = (int*)(pre + entries);
    const size_t ctrlBytes = (size_t)NBLK * sizeof(int) + NSTRIPE * sizeof(int);
    const size_t needed = 3 * entries * sizeof(float4) + ctrlBytes;

    if (ws_size >= needed) {
        hipMemsetAsync(flags, 0, ctrlBytes, stream);
        int* tickets = flags + NBLK;
        gae_onepass<<<NBLK, 256, 0, stream>>>(
            rewards, values, dones, aggA, aggP, pre, flags, tickets, out);
    } else {
        // Fallback: proven 2-kernel path (A/P reuse the first 4 MiB).
        float4* A = (float4*)d_ws;
        float4* P = A + (size_t)FB_CHUNKS * NV4;
        gae_phase1_fb <<<(FB_CHUNKS * NV4) / 256, 256, 0, stream>>>(
            rewards, values, dones, A, P);
        gae_phase23_fb<<<(FB_CHUNKS * NV4) / 256, 256, 0, stream>>>(
            rewards, values, dones, A, P, out);
    }
}

// Round 6
// 167.983 us; speedup vs baseline: 13.5329x; 13.5329x over previous
//
#include <hip/hip_runtime.h>

// GAE scan: T=2048, N=4096, fp32. 3-kernel chunked scan at C=128.
//
// Round-5 post-mortem: decoupled lookback = 2227us (13x worse). Every
// inter-block wait (fence + agent-scope flag hop) costs ~us on MI355X;
// deep lookback chains serialize the machine. CONFIRMED 3x (rounds 2,3,5):
// only zero-wait structures are viable; kernel boundaries are the only
// cheap global barrier.
//
// This version = round-0's two PROVEN streaming kernels + round-4's PROVEN
// scan kernel, at C=128 (round 4 used C=512: 3x16MB intermediates + 9-level
// 512-wide scan made it net-slower than round 0's O(C^2) lookback; at C=128
// intermediates are 2MB each and the scan is 7 levels of 128 threads).
//   K1 gae_sum : per-(chunk, env4) affine (A,P). 512 blocks, 50 indep
//                float4 loads/thread -> BW-bound (~16-18us).
//   K2 gae_scan: per-column suffix scan of 128 chunk affines in LDS
//                (Hillis-Steele, 7 levels). Inc[c][n4] = adv entering chunk
//                c. 4MB L2-hot r/w (~3-5us).
//   K3 gae_out : adv = Inc[idx], replay 16 steps (inputs L3-hot from K1),
//                write advantages + returns (~25-30us). No lookback.

#define T_LEN    2048
#define N_ENV    4096
#define NV4      (N_ENV / 4)          // 1024 float4 columns
#define N_CHUNKS 128
#define CHUNK_L  (T_LEN / N_CHUNKS)   // 16
#define NBLK     ((N_CHUNKS * NV4) / 256)   // 512 blocks

static constexpr float GAMMA = 0.99f;
static constexpr float GL    = 0.99f * 0.95f;   // gamma * gae_lambda

// ---- K1: per-chunk affine composition (verbatim round-0 phase1, PASSED) ---
__global__ __launch_bounds__(256) void gae_sum(
    const float4* __restrict__ rewards,   // [T_LEN][NV4]
    const float4* __restrict__ values,
    const float4* __restrict__ dones,
    float4* __restrict__ Aout,            // [N_CHUNKS][NV4]
    float4* __restrict__ Pout)
{
    const int idx = blockIdx.x * blockDim.x + threadIdx.x;   // c*NV4 + n4
    const int n4 = idx & (NV4 - 1);
    const int c  = idx >> 10;
    const int t_hi = c * CHUNK_L + (CHUNK_L - 1);

    float4 v_next, d_next;
    if (c == N_CHUNKS - 1) {
        v_next = make_float4(0.f, 0.f, 0.f, 0.f);
        d_next = make_float4(1.f, 1.f, 1.f, 1.f);
    } else {
        v_next = values[(t_hi + 1) * NV4 + n4];
        d_next = dones [(t_hi + 1) * NV4 + n4];
    }

    float4 A = make_float4(1.f, 1.f, 1.f, 1.f);
    float4 P = make_float4(0.f, 0.f, 0.f, 0.f);

    #pragma unroll
    for (int i = 0; i < CHUNK_L; ++i) {
        const int t = t_hi - i;
        const float4 r = rewards[t * NV4 + n4];
        const float4 v = values [t * NV4 + n4];
        const float4 d = dones  [t * NV4 + n4];
        #define STEP(X) { \
            const float nt    = 1.0f - d_next.X; \
            const float delta = fmaf(GAMMA * v_next.X, nt, r.X) - v.X; \
            const float co    = GL * nt; \
            P.X = fmaf(co, P.X, delta); \
            A.X = co * A.X; \
            v_next.X = v.X; d_next.X = d.X; }
        STEP(x) STEP(y) STEP(z) STEP(w)
        #undef STEP
    }
    Aout[idx] = A;
    Pout[idx] = P;
}

// ---- K2: per-column suffix scan (round-4 logic, PASSED; C=128, 7 levels) --
// Thread c holds f_c = (A,P); S_c = f_c o f_{c+1} o ... o f_{C-1};
// Inc[c] = S_{c+1}.P (adv entering chunk c). Combine (outer o inner):
// (a1,p1) o (a2,p2) = (a1*a2, a1*p2 + p1).
__global__ __launch_bounds__(128) void gae_scan(
    const float4* __restrict__ Ain,    // [N_CHUNKS][NV4]
    const float4* __restrict__ Pin,
    float4* __restrict__ Inc)          // [N_CHUNKS][NV4]
{
    __shared__ float4 sA[2][N_CHUNKS];   // 4 KB
    __shared__ float4 sP[2][N_CHUNKS];   // 4 KB
    const int n4 = blockIdx.x;
    const int c  = threadIdx.x;

    float4 a = Ain[c * NV4 + n4];
    float4 p = Pin[c * NV4 + n4];
    int cur = 0;
    sA[0][c] = a; sP[0][c] = p;
    __syncthreads();

    #pragma unroll
    for (int d = 1; d < N_CHUNKS; d <<= 1) {
        float4 na = a, np = p;
        if (c + d < N_CHUNKS) {
            const float4 a2 = sA[cur][c + d];
            const float4 p2 = sP[cur][c + d];
            na.x = a.x * a2.x;  np.x = fmaf(a.x, p2.x, p.x);
            na.y = a.y * a2.y;  np.y = fmaf(a.y, p2.y, p.y);
            na.z = a.z * a2.z;  np.z = fmaf(a.z, p2.z, p.z);
            na.w = a.w * a2.w;  np.w = fmaf(a.w, p2.w, p.w);
        }
        sA[cur ^ 1][c] = na; sP[cur ^ 1][c] = np;
        __syncthreads();
        a = na; p = np; cur ^= 1;
    }

    float4 inc = (c == N_CHUNKS - 1) ? make_float4(0.f, 0.f, 0.f, 0.f)
                                     : sP[cur][c + 1];
    Inc[c * NV4 + n4] = inc;
}

// ---- K3: replay with exact incoming advantage (round-0 phase23 minus
//          lookback, PASSED both pieces) ----------------------------------
__global__ __launch_bounds__(256) void gae_out(
    const float4* __restrict__ rewards,
    const float4* __restrict__ values,
    const float4* __restrict__ dones,
    const float4* __restrict__ Inc,
    float4* __restrict__ out)          // [2*T_LEN][NV4]: advantages, returns
{
    const int idx = blockIdx.x * blockDim.x + threadIdx.x;
    const int n4 = idx & (NV4 - 1);
    const int c  = idx >> 10;
    const int t_hi = c * CHUNK_L + (CHUNK_L - 1);

    float4 adv = Inc[idx];

    float4 v_next, d_next;
    if (c == N_CHUNKS - 1) {
        v_next = make_float4(0.f, 0.f, 0.f, 0.f);
        d_next = make_float4(1.f, 1.f, 1.f, 1.f);
    } else {
        v_next = values[(t_hi + 1) * NV4 + n4];
        d_next = dones [(t_hi + 1) * NV4 + n4];
    }

    #pragma unroll
    for (int i = 0; i < CHUNK_L; ++i) {
        const int t = t_hi - i;
        const float4 r = rewards[t * NV4 + n4];
        const float4 v = values [t * NV4 + n4];
        const float4 d = dones  [t * NV4 + n4];
        float4 ret;
        #define STEP(X) { \
            const float nt    = 1.0f - d_next.X; \
            const float delta = fmaf(GAMMA * v_next.X, nt, r.X) - v.X; \
            const float co    = GL * nt; \
            adv.X = fmaf(co, adv.X, delta); \
            ret.X = adv.X + v.X; \
            v_next.X = v.X; d_next.X = d.X; }
        STEP(x) STEP(y) STEP(z) STEP(w)
        #undef STEP
        out[t * NV4 + n4]           = adv;   // advantages
        out[(T_LEN + t) * NV4 + n4] = ret;   // returns
    }
}

// ---- fallback: proven round-0 2-kernel path (used only if ws too small) ---
__global__ __launch_bounds__(256) void gae_phase23_fb(
    const float4* __restrict__ rewards,
    const float4* __restrict__ values,
    const float4* __restrict__ dones,
    const float4* __restrict__ Ain,
    const float4* __restrict__ Pin,
    float4* __restrict__ out)
{
    const int idx = blockIdx.x * blockDim.x + threadIdx.x;
    const int n4 = idx & (NV4 - 1);
    const int c  = idx >> 10;
    const int t_hi = c * CHUNK_L + (CHUNK_L - 1);

    float4 adv = make_float4(0.f, 0.f, 0.f, 0.f);
    #pragma unroll 4
    for (int c2 = N_CHUNKS - 1; c2 > c; --c2) {
        const float4 a = Ain[c2 * NV4 + n4];
        const float4 p = Pin[c2 * NV4 + n4];
        adv.x = fmaf(a.x, adv.x, p.x);
        adv.y = fmaf(a.y, adv.y, p.y);
        adv.z = fmaf(a.z, adv.z, p.z);
        adv.w = fmaf(a.w, adv.w, p.w);
    }
    float4 v_next, d_next;
    if (c == N_CHUNKS - 1) {
        v_next = make_float4(0.f, 0.f, 0.f, 0.f);
        d_next = make_float4(1.f, 1.f, 1.f, 1.f);
    } else {
        v_next = values[(t_hi + 1) * NV4 + n4];
        d_next = dones [(t_hi + 1) * NV4 + n4];
    }
    #pragma unroll
    for (int i = 0; i < CHUNK_L; ++i) {
        const int t = t_hi - i;
        const float4 r = rewards[t * NV4 + n4];
        const float4 v = values [t * NV4 + n4];
        const float4 d = dones  [t * NV4 + n4];
        float4 ret;
        #define STEP(X) { \
            const float nt    = 1.0f - d_next.X; \
            const float delta = fmaf(GAMMA * v_next.X, nt, r.X) - v.X; \
            const float co    = GL * nt; \
            adv.X = fmaf(co, adv.X, delta); \
            ret.X = adv.X + v.X; \
            v_next.X = v.X; d_next.X = d.X; }
        STEP(x) STEP(y) STEP(z) STEP(w)
        #undef STEP
        out[t * NV4 + n4]           = adv;
        out[(T_LEN + t) * NV4 + n4] = ret;
    }
}

extern "C" void kernel_launch(void* const* d_in, const int* in_sizes, int n_in,
                              void* d_out, int out_size, void* d_ws, size_t ws_size,
                              hipStream_t stream) {
    const float4* rewards = (const float4*)d_in[0];
    const float4* values  = (const float4*)d_in[1];
    const float4* dones   = (const float4*)d_in[2];
    float4* out = (float4*)d_out;

    // Workspace: A | P | Inc, each N_CHUNKS*NV4 float4 = 2 MiB (6 MiB total).
    // All fully written before read (0xAA poison safe). No memsets, no
    // atomics, no inter-block waiting anywhere.
    const size_t entries = (size_t)N_CHUNKS * NV4;
    float4* A   = (float4*)d_ws;
    float4* P   = A + entries;
    float4* Inc = P + entries;

    if (ws_size >= 3 * entries * sizeof(float4)) {
        gae_sum <<<NBLK, 256, 0, stream>>>(rewards, values, dones, A, P);
        gae_scan<<<NV4,  128, 0, stream>>>(A, P, Inc);
        gae_out <<<NBLK, 256, 0, stream>>>(rewards, values, dones, Inc, out);
    } else {
        gae_sum      <<<NBLK, 256, 0, stream>>>(rewards, values, dones, A, P);
        gae_phase23_fb<<<NBLK, 256, 0, stream>>>(rewards, values, dones, A, P, out);
    }
}